// Round 7
// baseline (1703.328 us; speedup 1.0000x reference)
//
#include <hip/hip_runtime.h>

// FlexibleLiteMLA: qkv 1x1 conv -> dw5x5+grouped-pw -> linear attention -> proj 1x1 conv + BN
// Round 7 (identical resubmit of round 6 — container infra failure, no data).
// FULL FP32 pipeline, batch-chunked (2 batches/chunk x 4 chunks) to fit ws.
// Rationale: fp16 intermediates left absmax 1.29e-2 (>9.6e-3) due to heavy-tailed
// attention-ratio amplification of ~5e-4 quantization noise. fp32 everywhere removes it.
// ws per chunk (reused across 4 sequential chunks, fixed addresses):
//   qkv f32 [2][1536][4096] @0          (50331648 B)
//   agg f32 [2][1536][4096] @50331648   (50331648 B)
//   att f32 [2][1024][4096] @100663296  (33554432 B)
//   kv  f32 [2][128][72]    @134217728  (73728 B)     total 134291456 B (~134 MB)

#define CB    2      // batches per chunk
#define NCHNK 4
#define CIN   512
#define HWPX  4096
#define CQKV  1536
#define NH    128
#define CATT  1024
#define COUT  512

// ---------------- Kernel 1: qkv = W[1536,512] @ X[bz][512,4096] ----------------
__global__ __launch_bounds__(256) void k_qkv(const float* __restrict__ X,
                                             const float* __restrict__ Wq,
                                             float* __restrict__ qkv) {
    const int bz = blockIdx.z;
    const int m0 = blockIdx.y * 128;
    const int n0 = blockIdx.x * 128;
    const int t  = threadIdx.x;
    const int tx = t & 15, ty = t >> 4;
    __shared__ float As[16][132];
    __shared__ float Bs[16][128];
    const float* Xb = X + (size_t)bz * CIN * HWPX;

    float acc[8][8];
    #pragma unroll
    for (int i = 0; i < 8; ++i)
        #pragma unroll
        for (int j = 0; j < 8; ++j) acc[i][j] = 0.f;

    for (int k0 = 0; k0 < CIN; k0 += 16) {
        #pragma unroll
        for (int it = 0; it < 8; ++it) {           // A tile: 128 rows x 16 k
            int off = it * 256 + t;
            int r = off >> 4, kk = off & 15;
            As[kk][r] = Wq[(size_t)(m0 + r) * CIN + k0 + kk];
        }
        #pragma unroll
        for (int it = 0; it < 8; ++it) {           // B tile: 16 k x 128 n
            int off = it * 256 + t;
            int kk = off >> 7, c = off & 127;
            Bs[kk][c] = Xb[(size_t)(k0 + kk) * HWPX + n0 + c];
        }
        __syncthreads();
        #pragma unroll
        for (int kk = 0; kk < 16; ++kk) {
            float a[8], bb[8];
            #pragma unroll
            for (int i = 0; i < 8; ++i) a[i] = As[kk][ty * 8 + i];
            #pragma unroll
            for (int j = 0; j < 8; ++j) bb[j] = Bs[kk][tx * 8 + j];
            #pragma unroll
            for (int i = 0; i < 8; ++i)
                #pragma unroll
                for (int j = 0; j < 8; ++j) acc[i][j] += a[i] * bb[j];
        }
        __syncthreads();
    }
    #pragma unroll
    for (int i = 0; i < 8; ++i) {
        int m = m0 + ty * 8 + i;
        float* dst = &qkv[((size_t)bz * CQKV + m) * HWPX + n0 + tx * 8];
        float4 r0 = make_float4(acc[i][0], acc[i][1], acc[i][2], acc[i][3]);
        float4 r1 = make_float4(acc[i][4], acc[i][5], acc[i][6], acc[i][7]);
        *(float4*)dst       = r0;
        *(float4*)(dst + 4) = r1;
    }
}

// ------------- Kernel 2: fused depthwise 5x5 (pad 2) + grouped pw 8->8 -------------
__global__ __launch_bounds__(256) void k_dwpw(const float* __restrict__ qkv,
                                              const float* __restrict__ Wdw,
                                              const float* __restrict__ Wpw,
                                              float* __restrict__ agg) {
    const int bz = blockIdx.z;
    const int g = blockIdx.y;            // group 0..191 (8 channels each)
    const int tile = blockIdx.x;         // 16 tiles of 16x16 pixels
    const int ty0 = (tile >> 2) * 16, tx0 = (tile & 3) * 16;
    const int t = threadIdx.x;
    __shared__ float in[8][20][20];
    __shared__ float wdw[8][25];
    __shared__ float wpw[8][8];

    if (t < 200) wdw[t / 25][t % 25] = Wdw[(size_t)g * 200 + t];
    if (t < 64)  wpw[t >> 3][t & 7]  = Wpw[(size_t)g * 64 + t];

    const float* src = qkv + ((size_t)bz * CQKV + g * 8) * HWPX;
    for (int idx = t; idx < 3200; idx += 256) {
        int ch = idx / 400, rem = idx % 400;
        int r = rem / 20, c = rem % 20;
        int gy = ty0 + r - 2, gx = tx0 + c - 2;
        float v = 0.f;
        if (gy >= 0 && gy < 64 && gx >= 0 && gx < 64)
            v = src[(size_t)ch * HWPX + gy * 64 + gx];
        in[ch][r][c] = v;
    }
    __syncthreads();

    const int py = t >> 4, px = t & 15;
    float dwv[8];
    #pragma unroll
    for (int ch = 0; ch < 8; ++ch) {
        float s = 0.f;
        #pragma unroll
        for (int dy = 0; dy < 5; ++dy)
            #pragma unroll
            for (int dx = 0; dx < 5; ++dx)
                s += wdw[ch][dy * 5 + dx] * in[ch][py + dy][px + dx];
        dwv[ch] = s;
    }
    const int p = (ty0 + py) * 64 + tx0 + px;
    float* dst = agg + ((size_t)bz * CQKV + g * 8) * HWPX + p;
    #pragma unroll
    for (int j = 0; j < 8; ++j) {
        float s = 0.f;
        #pragma unroll
        for (int i = 0; i < 8; ++i) s += wpw[j][i] * dwv[i];
        dst[(size_t)j * HWPX] = s;
    }
}

// ------------- Kernel 3: kv[bz][h][d][e] = sum_n relu(k)*[v,1] -------------
__global__ __launch_bounds__(256) void k_kv(const float* __restrict__ qkv,
                                            const float* __restrict__ agg,
                                            float* __restrict__ kv) {
    const int h = blockIdx.x;
    const int bz = blockIdx.y;
    const int t = threadIdx.x;
    const float* base = (h < 64) ? (qkv + ((size_t)bz * CQKV + h * 24) * HWPX)
                                 : (agg + ((size_t)bz * CQKV + (h - 64) * 24) * HWPX);
    float acc[8][9];
    #pragma unroll
    for (int d = 0; d < 8; ++d)
        #pragma unroll
        for (int e = 0; e < 9; ++e) acc[d][e] = 0.f;

    for (int it = 0; it < 16; ++it) {
        int p = it * 256 + t;
        float kk[8], vv[8];
        #pragma unroll
        for (int d = 0; d < 8; ++d) kk[d] = fmaxf(base[(size_t)(8 + d) * HWPX + p], 0.f);
        #pragma unroll
        for (int e = 0; e < 8; ++e) vv[e] = base[(size_t)(16 + e) * HWPX + p];
        #pragma unroll
        for (int d = 0; d < 8; ++d) {
            #pragma unroll
            for (int e = 0; e < 8; ++e) acc[d][e] += kk[d] * vv[e];
            acc[d][8] += kk[d];
        }
    }
    __shared__ float part[4][72];
    const int wave = t >> 6;
    #pragma unroll
    for (int d = 0; d < 8; ++d)
        #pragma unroll
        for (int e = 0; e < 9; ++e) {
            float v = acc[d][e];
            #pragma unroll
            for (int off = 32; off; off >>= 1) v += __shfl_down(v, off, 64);
            if ((t & 63) == 0) part[wave][d * 9 + e] = v;
        }
    __syncthreads();
    if (t < 72) {
        float s = part[0][t] + part[1][t] + part[2][t] + part[3][t];
        kv[((size_t)bz * NH + h) * 72 + t] = s;
    }
}

// ------------- Kernel 4: att[bz][h*8+d][p] = (relu(q)·kv[:,d]) / (relu(q)·kv[:,8] + eps) -------------
__global__ __launch_bounds__(256) void k_att(const float* __restrict__ qkv,
                                             const float* __restrict__ agg,
                                             const float* __restrict__ kv,
                                             float* __restrict__ att) {
    const int h = blockIdx.y, bz = blockIdx.z;
    const int p = blockIdx.x * 256 + threadIdx.x;
    __shared__ float kvs[72];
    if (threadIdx.x < 72) kvs[threadIdx.x] = kv[((size_t)bz * NH + h) * 72 + threadIdx.x];
    __syncthreads();
    const float* base = (h < 64) ? (qkv + ((size_t)bz * CQKV + h * 24) * HWPX)
                                 : (agg + ((size_t)bz * CQKV + (h - 64) * 24) * HWPX);
    float q[8];
    #pragma unroll
    for (int d = 0; d < 8; ++d) q[d] = fmaxf(base[(size_t)d * HWPX + p], 0.f);
    float num[9];
    #pragma unroll
    for (int e = 0; e < 9; ++e) {
        float s = 0.f;
        #pragma unroll
        for (int d = 0; d < 8; ++d) s += q[d] * kvs[d * 9 + e];
        num[e] = s;
    }
    const float inv = 1.f / (num[8] + 1e-15f);
    float* dst = att + ((size_t)bz * CATT + h * 8) * HWPX + p;
    #pragma unroll
    for (int d = 0; d < 8; ++d) dst[(size_t)d * HWPX] = num[d] * inv;
}

// ------------- Kernel 5: out = BN(proj_w[512,1024] @ att[bz][1024,4096]) -------------
__global__ __launch_bounds__(256) void k_proj(const float* __restrict__ att,
                                              const float* __restrict__ Wp,
                                              const float* __restrict__ gamma,
                                              const float* __restrict__ beta,
                                              const float* __restrict__ mean,
                                              const float* __restrict__ var,
                                              float* __restrict__ out) {
    const int bz = blockIdx.z;
    const int m0 = blockIdx.y * 128;
    const int n0 = blockIdx.x * 128;
    const int t  = threadIdx.x;
    const int tx = t & 15, ty = t >> 4;
    __shared__ float As[16][132];
    __shared__ float Bs[16][128];
    const float* Bb = att + (size_t)bz * CATT * HWPX;

    float acc[8][8];
    #pragma unroll
    for (int i = 0; i < 8; ++i)
        #pragma unroll
        for (int j = 0; j < 8; ++j) acc[i][j] = 0.f;

    for (int k0 = 0; k0 < CATT; k0 += 16) {
        #pragma unroll
        for (int it = 0; it < 8; ++it) {
            int off = it * 256 + t;
            int r = off >> 4, kk = off & 15;
            As[kk][r] = Wp[(size_t)(m0 + r) * CATT + k0 + kk];
        }
        #pragma unroll
        for (int it = 0; it < 8; ++it) {
            int off = it * 256 + t;
            int kk = off >> 7, c = off & 127;
            Bs[kk][c] = Bb[(size_t)(k0 + kk) * HWPX + n0 + c];
        }
        __syncthreads();
        #pragma unroll
        for (int kk = 0; kk < 16; ++kk) {
            float a[8], bb[8];
            #pragma unroll
            for (int i = 0; i < 8; ++i) a[i] = As[kk][ty * 8 + i];
            #pragma unroll
            for (int j = 0; j < 8; ++j) bb[j] = Bs[kk][tx * 8 + j];
            #pragma unroll
            for (int i = 0; i < 8; ++i)
                #pragma unroll
                for (int j = 0; j < 8; ++j) acc[i][j] += a[i] * bb[j];
        }
        __syncthreads();
    }
    #pragma unroll
    for (int i = 0; i < 8; ++i) {
        const int m = m0 + ty * 8 + i;
        const float iv = rsqrtf(var[m] + 1e-5f) * gamma[m];
        const float ad = beta[m] - mean[m] * iv;
        float* dst = out + ((size_t)bz * COUT + m) * HWPX + n0 + tx * 8;
        float4 r0 = make_float4(acc[i][0] * iv + ad, acc[i][1] * iv + ad,
                                acc[i][2] * iv + ad, acc[i][3] * iv + ad);
        float4 r1 = make_float4(acc[i][4] * iv + ad, acc[i][5] * iv + ad,
                                acc[i][6] * iv + ad, acc[i][7] * iv + ad);
        *(float4*)dst       = r0;
        *(float4*)(dst + 4) = r1;
    }
}

extern "C" void kernel_launch(void* const* d_in, const int* in_sizes, int n_in,
                              void* d_out, int out_size, void* d_ws, size_t ws_size,
                              hipStream_t stream) {
    const float* x      = (const float*)d_in[0];
    const float* qkv_w  = (const float*)d_in[1];
    const float* dw_w   = (const float*)d_in[2];
    const float* pw_w   = (const float*)d_in[3];
    const float* proj_w = (const float*)d_in[4];
    const float* gamma  = (const float*)d_in[5];
    const float* beta   = (const float*)d_in[6];
    const float* mean   = (const float*)d_in[7];
    const float* var    = (const float*)d_in[8];
    float* out = (float*)d_out;

    char* ws = (char*)d_ws;
    float* qkv = (float*)(ws);
    float* agg = (float*)(ws + 50331648);
    float* att = (float*)(ws + 100663296);
    float* kv  = (float*)(ws + 134217728);

    for (int c = 0; c < NCHNK; ++c) {
        const float* xc  = x   + (size_t)c * CB * CIN  * HWPX;
        float*      outc = out + (size_t)c * CB * COUT * HWPX;
        k_qkv <<<dim3(32, 12, CB), 256, 0, stream>>>(xc, qkv_w, qkv);
        k_dwpw<<<dim3(16, 192, CB), 256, 0, stream>>>(qkv, dw_w, pw_w, agg);
        k_kv  <<<dim3(NH, CB),      256, 0, stream>>>(qkv, agg, kv);
        k_att <<<dim3(16, NH, CB),  256, 0, stream>>>(qkv, agg, kv, att);
        k_proj<<<dim3(32, 4, CB),   256, 0, stream>>>(att, proj_w, gamma, beta, mean, var, outc);
    }
}

// Round 9
// 895.914 us; speedup vs baseline: 1.9012x; 1.9012x over previous
//
#include <hip/hip_runtime.h>

// FlexibleLiteMLA: qkv 1x1 conv -> dw5x5+grouped-pw -> linear attention -> proj 1x1 conv + BN
// Round 9 (identical resubmit of round 8 — GPU acquisition timeout, no data).
// Split-fp16 MFMA for both GEMMs (3-term h/l decomposition ~= fp32 accuracy).
// Pipeline/storage stays fp32 (round-7 green baseline: absmax 1.95e-3, 1703us).
// ws per chunk (2 batches/chunk x 4 chunks, fixed addresses):
//   qkv f32 [2][1536][4096] @0          (50331648 B)
//   agg f32 [2][1536][4096] @50331648   (50331648 B)
//   att f32 [2][1024][4096] @100663296  (33554432 B)
//   kv  f32 [2][128][72]    @134217728  (73728 B)     total ~134 MB

#define CB    2
#define NCHNK 4
#define CIN   512
#define HWPX  4096
#define CQKV  1536
#define NH    128
#define CATT  1024
#define COUT  512

typedef _Float16 f16x8 __attribute__((ext_vector_type(8)));
typedef float    f32x4 __attribute__((ext_vector_type(4)));

// ---------------- Split-fp16 MFMA GEMM: C[M][4096] = A[M][K] @ B[bz][K][4096] ----------------
// 128x128 tile, BK=32, 4 waves (2x2 of 64x64), mfma_f32_16x16x32_f16, 3 split terms.
// A operand layout per lane: row=lane&15, k=8*(lane>>4)+j ; B: col=lane&15, same k.
// C/D: col=lane&15, row=4*(lane>>4)+reg  [verified m89 mapping].
template<int K, int CMSTR, bool PROJ>
__global__ __launch_bounds__(256) void k_gemm(const float* __restrict__ A,
                                              const float* __restrict__ B,
                                              float* __restrict__ C,
                                              const float* __restrict__ gamma,
                                              const float* __restrict__ beta,
                                              const float* __restrict__ mean,
                                              const float* __restrict__ var) {
    const int bz = blockIdx.z;
    const int m0 = blockIdx.y * 128;
    const int n0 = blockIdx.x * 128;
    const int t  = threadIdx.x;

    __shared__ _Float16 Ah[128][40], Al[128][40];   // [m][k] pad->40 (16B aligned rows)
    __shared__ _Float16 Bh[128][40], Bl[128][40];   // [n][k]
    __shared__ float ivs[128], ads[128];

    if (PROJ && t < 128) {
        int m = m0 + t;
        float iv = rsqrtf(var[m] + 1e-5f) * gamma[m];
        ivs[t] = iv;
        ads[t] = beta[m] - mean[m] * iv;
    }

    const float* Bb = B + (size_t)bz * K * HWPX;

    f32x4 acc[4][4];
    #pragma unroll
    for (int i = 0; i < 4; ++i)
        #pragma unroll
        for (int j = 0; j < 4; ++j) acc[i][j] = (f32x4)0.f;

    const int lane = t & 63;
    const int wv   = t >> 6;
    const int wr   = (wv >> 1) * 64;
    const int wc   = (wv & 1) * 64;
    const int lrow = lane & 15;
    const int lk   = (lane >> 4) * 8;

    for (int k0 = 0; k0 < K; k0 += 32) {
        // ---- stage A tile: 128 rows x 32 k, split into h/l ----
        {
            const int row = t >> 1, kh = (t & 1) * 16;
            const float* src = A + (size_t)(m0 + row) * K + k0 + kh;
            #pragma unroll
            for (int q = 0; q < 4; ++q) {
                float4 v = *(const float4*)(src + q * 4);
                float vv[4] = {v.x, v.y, v.z, v.w};
                #pragma unroll
                for (int j = 0; j < 4; ++j) {
                    float x = vv[j];
                    _Float16 h = (_Float16)x;
                    Ah[row][kh + q * 4 + j] = h;
                    Al[row][kh + q * 4 + j] = (_Float16)(x - (float)h);
                }
            }
        }
        // ---- stage B tile transposed: [n][k], coalesced k-row loads ----
        {
            const int n = t & 127, kg = (t >> 7) * 8;
            #pragma unroll
            for (int pass = 0; pass < 2; ++pass) {
                const int ko = kg + pass * 16;      // {0,8,16,24} across threads/passes
                f16x8 hb, lb;
                #pragma unroll
                for (int i = 0; i < 8; ++i) {
                    float x = Bb[(size_t)(k0 + ko + i) * HWPX + n0 + n];
                    _Float16 h = (_Float16)x;
                    hb[i] = h;
                    lb[i] = (_Float16)(x - (float)h);
                }
                *(f16x8*)&Bh[n][ko] = hb;
                *(f16x8*)&Bl[n][ko] = lb;
            }
        }
        __syncthreads();

        // ---- fragments + 3-term MFMA ----
        f16x8 ah[4], al[4], bh[4], bl[4];
        #pragma unroll
        for (int rb = 0; rb < 4; ++rb) {
            ah[rb] = *(const f16x8*)&Ah[wr + rb * 16 + lrow][lk];
            al[rb] = *(const f16x8*)&Al[wr + rb * 16 + lrow][lk];
        }
        #pragma unroll
        for (int cb = 0; cb < 4; ++cb) {
            bh[cb] = *(const f16x8*)&Bh[wc + cb * 16 + lrow][lk];
            bl[cb] = *(const f16x8*)&Bl[wc + cb * 16 + lrow][lk];
        }
        #pragma unroll
        for (int rb = 0; rb < 4; ++rb)
            #pragma unroll
            for (int cb = 0; cb < 4; ++cb) {
                acc[rb][cb] = __builtin_amdgcn_mfma_f32_16x16x32_f16(ah[rb], bh[cb], acc[rb][cb], 0, 0, 0);
                acc[rb][cb] = __builtin_amdgcn_mfma_f32_16x16x32_f16(ah[rb], bl[cb], acc[rb][cb], 0, 0, 0);
                acc[rb][cb] = __builtin_amdgcn_mfma_f32_16x16x32_f16(al[rb], bh[cb], acc[rb][cb], 0, 0, 0);
            }
        __syncthreads();
    }

    // ---- epilogue ----
    #pragma unroll
    for (int rb = 0; rb < 4; ++rb) {
        #pragma unroll
        for (int reg = 0; reg < 4; ++reg) {
            const int mloc = wr + rb * 16 + (lane >> 4) * 4 + reg;
            float* dst = C + ((size_t)bz * CMSTR + m0 + mloc) * HWPX + n0 + wc + (lane & 15);
            if (PROJ) {
                const float iv = ivs[mloc], ad = ads[mloc];
                #pragma unroll
                for (int cb = 0; cb < 4; ++cb) dst[cb * 16] = acc[rb][cb][reg] * iv + ad;
            } else {
                #pragma unroll
                for (int cb = 0; cb < 4; ++cb) dst[cb * 16] = acc[rb][cb][reg];
            }
        }
    }
}

// ------------- Kernel 2: fused depthwise 5x5 (pad 2) + grouped pw 8->8 -------------
__global__ __launch_bounds__(256) void k_dwpw(const float* __restrict__ qkv,
                                              const float* __restrict__ Wdw,
                                              const float* __restrict__ Wpw,
                                              float* __restrict__ agg) {
    const int bz = blockIdx.z;
    const int g = blockIdx.y;
    const int tile = blockIdx.x;
    const int ty0 = (tile >> 2) * 16, tx0 = (tile & 3) * 16;
    const int t = threadIdx.x;
    __shared__ float in[8][20][20];
    __shared__ float wdw[8][25];
    __shared__ float wpw[8][8];

    if (t < 200) wdw[t / 25][t % 25] = Wdw[(size_t)g * 200 + t];
    if (t < 64)  wpw[t >> 3][t & 7]  = Wpw[(size_t)g * 64 + t];

    const float* src = qkv + ((size_t)bz * CQKV + g * 8) * HWPX;
    for (int idx = t; idx < 3200; idx += 256) {
        int ch = idx / 400, rem = idx % 400;
        int r = rem / 20, c = rem % 20;
        int gy = ty0 + r - 2, gx = tx0 + c - 2;
        float v = 0.f;
        if (gy >= 0 && gy < 64 && gx >= 0 && gx < 64)
            v = src[(size_t)ch * HWPX + gy * 64 + gx];
        in[ch][r][c] = v;
    }
    __syncthreads();

    const int py = t >> 4, px = t & 15;
    float dwv[8];
    #pragma unroll
    for (int ch = 0; ch < 8; ++ch) {
        float s = 0.f;
        #pragma unroll
        for (int dy = 0; dy < 5; ++dy)
            #pragma unroll
            for (int dx = 0; dx < 5; ++dx)
                s += wdw[ch][dy * 5 + dx] * in[ch][py + dy][px + dx];
        dwv[ch] = s;
    }
    const int p = (ty0 + py) * 64 + tx0 + px;
    float* dst = agg + ((size_t)bz * CQKV + g * 8) * HWPX + p;
    #pragma unroll
    for (int j = 0; j < 8; ++j) {
        float s = 0.f;
        #pragma unroll
        for (int i = 0; i < 8; ++i) s += wpw[j][i] * dwv[i];
        dst[(size_t)j * HWPX] = s;
    }
}

// ------------- Kernel 3: kv[bz][h][d][e] = sum_n relu(k)*[v,1] -------------
__global__ __launch_bounds__(256) void k_kv(const float* __restrict__ qkv,
                                            const float* __restrict__ agg,
                                            float* __restrict__ kv) {
    const int h = blockIdx.x;
    const int bz = blockIdx.y;
    const int t = threadIdx.x;
    const float* base = (h < 64) ? (qkv + ((size_t)bz * CQKV + h * 24) * HWPX)
                                 : (agg + ((size_t)bz * CQKV + (h - 64) * 24) * HWPX);
    float acc[8][9];
    #pragma unroll
    for (int d = 0; d < 8; ++d)
        #pragma unroll
        for (int e = 0; e < 9; ++e) acc[d][e] = 0.f;

    for (int it = 0; it < 16; ++it) {
        int p = it * 256 + t;
        float kk[8], vv[8];
        #pragma unroll
        for (int d = 0; d < 8; ++d) kk[d] = fmaxf(base[(size_t)(8 + d) * HWPX + p], 0.f);
        #pragma unroll
        for (int e = 0; e < 8; ++e) vv[e] = base[(size_t)(16 + e) * HWPX + p];
        #pragma unroll
        for (int d = 0; d < 8; ++d) {
            #pragma unroll
            for (int e = 0; e < 8; ++e) acc[d][e] += kk[d] * vv[e];
            acc[d][8] += kk[d];
        }
    }
    __shared__ float part[4][72];
    const int wave = t >> 6;
    #pragma unroll
    for (int d = 0; d < 8; ++d)
        #pragma unroll
        for (int e = 0; e < 9; ++e) {
            float v = acc[d][e];
            #pragma unroll
            for (int off = 32; off; off >>= 1) v += __shfl_down(v, off, 64);
            if ((t & 63) == 0) part[wave][d * 9 + e] = v;
        }
    __syncthreads();
    if (t < 72) {
        float s = part[0][t] + part[1][t] + part[2][t] + part[3][t];
        kv[((size_t)bz * NH + h) * 72 + t] = s;
    }
}

// ------------- Kernel 4: att[bz][h*8+d][p] = (relu(q)·kv[:,d]) / (relu(q)·kv[:,8] + eps) -------------
__global__ __launch_bounds__(256) void k_att(const float* __restrict__ qkv,
                                             const float* __restrict__ agg,
                                             const float* __restrict__ kv,
                                             float* __restrict__ att) {
    const int h = blockIdx.y, bz = blockIdx.z;
    const int p = blockIdx.x * 256 + threadIdx.x;
    __shared__ float kvs[72];
    if (threadIdx.x < 72) kvs[threadIdx.x] = kv[((size_t)bz * NH + h) * 72 + threadIdx.x];
    __syncthreads();
    const float* base = (h < 64) ? (qkv + ((size_t)bz * CQKV + h * 24) * HWPX)
                                 : (agg + ((size_t)bz * CQKV + (h - 64) * 24) * HWPX);
    float q[8];
    #pragma unroll
    for (int d = 0; d < 8; ++d) q[d] = fmaxf(base[(size_t)d * HWPX + p], 0.f);
    float num[9];
    #pragma unroll
    for (int e = 0; e < 9; ++e) {
        float s = 0.f;
        #pragma unroll
        for (int d = 0; d < 8; ++d) s += q[d] * kvs[d * 9 + e];
        num[e] = s;
    }
    const float inv = 1.f / (num[8] + 1e-15f);
    float* dst = att + ((size_t)bz * CATT + h * 8) * HWPX + p;
    #pragma unroll
    for (int d = 0; d < 8; ++d) dst[(size_t)d * HWPX] = num[d] * inv;
}

extern "C" void kernel_launch(void* const* d_in, const int* in_sizes, int n_in,
                              void* d_out, int out_size, void* d_ws, size_t ws_size,
                              hipStream_t stream) {
    const float* x      = (const float*)d_in[0];
    const float* qkv_w  = (const float*)d_in[1];
    const float* dw_w   = (const float*)d_in[2];
    const float* pw_w   = (const float*)d_in[3];
    const float* proj_w = (const float*)d_in[4];
    const float* gamma  = (const float*)d_in[5];
    const float* beta   = (const float*)d_in[6];
    const float* mean   = (const float*)d_in[7];
    const float* var    = (const float*)d_in[8];
    float* out = (float*)d_out;

    char* ws = (char*)d_ws;
    float* qkv = (float*)(ws);
    float* agg = (float*)(ws + 50331648);
    float* att = (float*)(ws + 100663296);
    float* kv  = (float*)(ws + 134217728);

    for (int c = 0; c < NCHNK; ++c) {
        const float* xc  = x   + (size_t)c * CB * CIN  * HWPX;
        float*      outc = out + (size_t)c * CB * COUT * HWPX;
        k_gemm<512, CQKV, false><<<dim3(32, 12, CB), 256, 0, stream>>>(
            qkv_w, xc, qkv, nullptr, nullptr, nullptr, nullptr);
        k_dwpw<<<dim3(16, 192, CB), 256, 0, stream>>>(qkv, dw_w, pw_w, agg);
        k_kv  <<<dim3(NH, CB),      256, 0, stream>>>(qkv, agg, kv);
        k_att <<<dim3(16, NH, CB),  256, 0, stream>>>(qkv, agg, kv, att);
        k_gemm<1024, COUT, true><<<dim3(32, 4, CB), 256, 0, stream>>>(
            proj_w, att, outc, gamma, beta, mean, var);
    }
}